// Round 11
// baseline (124.551 us; speedup 1.0000x reference)
//
#include <hip/hip_runtime.h>
#include <hip/hip_bf16.h>

#define BB 64
#define NN 512
#define FD 64

typedef short bf16x8 __attribute__((ext_vector_type(8)));
typedef float f32x4 __attribute__((ext_vector_type(4)));

__device__ __forceinline__ float bf2f(unsigned short h){
    unsigned u = ((unsigned)h) << 16;
    return __builtin_bit_cast(float, u);
}
// packed f32x2 -> bf16x2 (RNE) via the official intrinsic; compiler emits
// v_cvt_pk_bf16_f32 on gfx950. (__hip_bfloat162 is not trivially copyable ->
// reinterpret via memcpy, which lowers to a plain register move.)
__device__ __forceinline__ unsigned pkbf2(float lo, float hi){
    __hip_bfloat162 h = __float22bfloat162_rn(make_float2(lo, hi));
    unsigned r;
    __builtin_memcpy(&r, &h, 4);
    return r;
}
__device__ __forceinline__ float fast_tanh(float x){
    float e = __expf(2.0f * x);                 // inf -> 1, 0 -> -1: saturates correctly
    return 1.0f - 2.0f * __builtin_amdgcn_rcpf(e + 1.0f);
}
__device__ __forceinline__ bf16x8 pack8(float4 a, float4 b){
    union { unsigned u[4]; bf16x8 v; } r;
    r.u[0] = pkbf2(a.x, a.y); r.u[1] = pkbf2(a.z, a.w);
    r.u[2] = pkbf2(b.x, b.y); r.u[3] = pkbf2(b.z, b.w);
    return r.v;
}

// v11 = v10 with the bit_cast->memcpy compile fix. Otherwise: v8 (last passing,
// best-measured, zero-workspace single dispatch) + conversion diet only
// (all f32->bf16 through __float22bfloat162_rn = HW v_cvt_pk_bf16_f32, RNE).
// Rowsum stays v8's proven shfl reduction. Layouts, fences, barriers, phase
// structure byte-identical to v8.
__global__ __launch_bounds__(512, 1) void k_fused(const float* __restrict__ X,
                                               const float* __restrict__ A,
                                               const float* __restrict__ W,
                                               const float* __restrict__ a,
                                               const int* __restrict__ Ni,
                                               const float* __restrict__ bias_a,
                                               const float* __restrict__ bias_W,
                                               float* __restrict__ H){
    __shared__ unsigned short XWtL[64][520];   // [f][n], row 1040B (16B-mult)
    __shared__ unsigned short XWhL[512][72];   // [n][f], row 144B  (16B-mult)
    __shared__ unsigned short Pl[8][16][72];   // per-wave M/P strip [i][f or j]
    __shared__ float bl[512];                  // bias_a
    __shared__ float csl[64];                  // colsum
    __shared__ float cpart[8][64];             // colsum partials
    int t = threadIdx.x;
    int b = blockIdx.x, it2 = blockIdx.y;
    int lane = t & 63, w = t >> 6, l15 = lane & 15, quad = lane >> 4;
    int tl = w >> 2, st = w & 3;
    int i0 = (it2 + 4*tl) * 64;
    int Nb = (Ni[1] == 0) ? Ni[2*b] : Ni[b];   // int64 vs int32 layout
    const float* Xb = X + (size_t)b*NN*FD;
    const float* Arow = A + (size_t)(b*NN + i0 + st*16 + l15)*NN + quad*8;

    // ---- prologue: issue X fragment loads first (deepest need) ----
    float4 xv[8][2];                           // wave w computes XW rows [64w, 64w+64)
    #pragma unroll
    for (int rt = 0; rt < 4; rt++)
        #pragma unroll
        for (int ks = 0; ks < 2; ks++){
            const float* p = &Xb[(w*64 + rt*16 + l15)*FD + ks*32 + quad*8];
            xv[rt*2 + ks][0] = *(const float4*)p;
            xv[rt*2 + ks][1] = *(const float4*)(p + 4);
        }
    // colsum partials: 8 parts x 64 cols, 8 rows of 'a' each (coalesced, L3-hot)
    {
        int part = t >> 6, d = t & 63;
        float s = 0.f;
        #pragma unroll
        for (int i = 0; i < 8; i++) s += a[(part*8 + i)*64 + d];
        cpart[part][d] = s;
    }
    // W^T fragments straight from global W (16KB, L3-hot): wf[ft][ks][j] = W[c][d]
    bf16x8 wf[4][2];
    #pragma unroll
    for (int ft = 0; ft < 4; ft++)
        #pragma unroll
        for (int ks = 0; ks < 2; ks++){
            union { unsigned u[4]; bf16x8 v; } r;
            #pragma unroll
            for (int m = 0; m < 4; m++)
                r.u[m] = pkbf2(W[(ks*32 + quad*8 + 2*m    )*64 + ft*16 + l15],
                               W[(ks*32 + quad*8 + 2*m + 1)*64 + ft*16 + l15]);
            wf[ft][ks] = r.v;
        }
    bl[t] = bias_a[t];
    __syncthreads();                           // barrier 1: cpart ready
    if (t < 64)
        csl[t] = ((cpart[0][t] + cpart[1][t]) + (cpart[2][t] + cpart[3][t]))
               + ((cpart[4][t] + cpart[5][t]) + (cpart[6][t] + cpart[7][t]));

    // ---- XW both orientations, packed b64 writes only (v5-verified) ----
    #pragma unroll
    for (int rt = 0; rt < 4; rt++){
        bf16x8 af0 = pack8(xv[rt*2][0],     xv[rt*2][1]);       // ks=0
        bf16x8 af1 = pack8(xv[rt*2 + 1][0], xv[rt*2 + 1][1]);   // ks=1
        f32x4 c[4]  = {{0,0,0,0},{0,0,0,0},{0,0,0,0},{0,0,0,0}};
        f32x4 ct[4] = {{0,0,0,0},{0,0,0,0},{0,0,0,0},{0,0,0,0}};
        #pragma unroll
        for (int nt = 0; nt < 4; nt++){
            c[nt]  = __builtin_amdgcn_mfma_f32_16x16x32_bf16(af0, wf[nt][0], c[nt], 0, 0, 0);
            c[nt]  = __builtin_amdgcn_mfma_f32_16x16x32_bf16(af1, wf[nt][1], c[nt], 0, 0, 0);
            ct[nt] = __builtin_amdgcn_mfma_f32_16x16x32_bf16(wf[nt][0], af0, ct[nt], 0, 0, 0);
            ct[nt] = __builtin_amdgcn_mfma_f32_16x16x32_bf16(wf[nt][1], af1, ct[nt], 0, 0, 0);
        }
        int n0 = w*64 + rt*16;
        #pragma unroll
        for (int nt = 0; nt < 4; nt++){        // XWtL[f][n]: n (=rg) in-lane -> b64
            uint2 pk = { pkbf2(c[nt][0], c[nt][1]), pkbf2(c[nt][2], c[nt][3]) };
            *(uint2*)&XWtL[nt*16 + l15][n0 + quad*4] = pk;
        }
        #pragma unroll
        for (int ft = 0; ft < 4; ft++){        // XWhL[n][f]: f (=rg) in-lane -> b64
            uint2 pk = { pkbf2(ct[ft][0], ct[ft][1]), pkbf2(ct[ft][2], ct[ft][3]) };
            *(uint2*)&XWhL[n0 + l15][ft*16 + quad*4] = pk;
        }
    }
    // A prefetch depth 8 (latency overlaps XW write drain + barrier)
    float4 pa[8][2];
    #pragma unroll
    for (int s = 0; s < 8; s++){
        pa[s][0] = *(const float4*)&Arow[s*32];
        pa[s][1] = *(const float4*)&Arow[s*32 + 4];
    }
    __syncthreads();                           // barrier 2: XW staged, csl ready

    // ---- phase A (swapped): Mt[f][i], i = l15, f = nt*16 + quad*4 + rg ----
    f32x4 acc[4] = {{0,0,0,0},{0,0,0,0},{0,0,0,0},{0,0,0,0}};
    float rs = 0.f;
    #pragma unroll
    for (int s = 0; s < 16; s++){
        float4 v0 = pa[s & 7][0], v1 = pa[s & 7][1];
        if (s < 8){                            // rotate prefetch 8 k-steps ahead
            pa[s & 7][0] = *(const float4*)&Arow[(s + 8)*32];
            pa[s & 7][1] = *(const float4*)&Arow[(s + 8)*32 + 4];
        }
        rs += (v0.x + v0.y) + (v0.z + v0.w) + (v1.x + v1.y) + (v1.z + v1.w);
        bf16x8 af = pack8(v0, v1);
        #pragma unroll
        for (int nt = 0; nt < 4; nt++){
            bf16x8 xa = *(const bf16x8*)&XWtL[nt*16 + l15][s*32 + quad*8];
            acc[nt] = __builtin_amdgcn_mfma_f32_16x16x32_bf16(xa, af, acc[nt], 0, 0, 0);
        }
    }
    int irow = i0 + st*16 + l15;               // this lane's i (output column)
    bool dg = irow < Nb;
    // diag add (b64 reads), colsum scale, M strip write (b64, row layout [i][f])
    #pragma unroll
    for (int nt = 0; nt < 4; nt++){
        float4 cs4 = *(const float4*)&csl[nt*16 + quad*4];
        ushort4 dh = *(const ushort4*)&XWhL[irow][nt*16 + quad*4];
        float m0 = (acc[nt][0] + (dg ? bf2f(dh.x) : 0.f)) * cs4.x;
        float m1 = (acc[nt][1] + (dg ? bf2f(dh.y) : 0.f)) * cs4.y;
        float m2 = (acc[nt][2] + (dg ? bf2f(dh.z) : 0.f)) * cs4.z;
        float m3 = (acc[nt][3] + (dg ? bf2f(dh.w) : 0.f)) * cs4.w;
        uint2 pk = { pkbf2(m0, m1), pkbf2(m2, m3) };
        *(uint2*)&Pl[w][l15][nt*16 + quad*4] = pk;
    }
    // in-wave rowsum: every lane ends holding rowsum(row i = l15)
    float rsum = rs;
    rsum += __shfl_xor(rsum, 16);
    rsum += __shfl_xor(rsum, 32);
    float rsum_l = rsum + (dg ? 1.f : 0.f);
    asm volatile("s_waitcnt lgkmcnt(0)" ::: "memory");
    __builtin_amdgcn_sched_barrier(0);
    bf16x8 maf[2];                             // M[i=l15][f-slice] -> GEMM1 B-operand
    maf[0] = *(const bf16x8*)&Pl[w][l15][quad*8];
    maf[1] = *(const bf16x8*)&Pl[w][l15][32 + quad*8];

    // ---- phase B: 8 j-chunks, wave-private, all-swapped ----
    f32x4 hacc[4] = {{0,0,0,0},{0,0,0,0},{0,0,0,0},{0,0,0,0}};
    float4 bwv[4];
    #pragma unroll
    for (int dt = 0; dt < 4; dt++) bwv[dt] = *(const float4*)&bias_W[dt*16 + quad*4];
    #pragma unroll
    for (int jt = 0; jt < 8; jt++){
        #pragma unroll
        for (int nt = 0; nt < 4; nt++){        // GEMM1 swapped: att^T (j rows, i=l15 cols)
            float4 blv = *(const float4*)&bl[jt*64 + nt*16 + quad*4];
            f32x4 arg = { rsum_l*blv.x, rsum_l*blv.y, rsum_l*blv.z, rsum_l*blv.w };
            #pragma unroll
            for (int ks = 0; ks < 2; ks++){
                bf16x8 xh = *(const bf16x8*)&XWhL[jt*64 + nt*16 + l15][ks*32 + quad*8];
                arg = __builtin_amdgcn_mfma_f32_16x16x32_bf16(xh, maf[ks], arg, 0, 0, 0);
            }
            uint2 pk = { pkbf2(fast_tanh(arg[0]), fast_tanh(arg[1])),
                         pkbf2(fast_tanh(arg[2]), fast_tanh(arg[3])) };
            *(uint2*)&Pl[w][l15][nt*16 + quad*4] = pk;   // P[i=l15][j-local], GEMM2-ready
        }
        asm volatile("s_waitcnt lgkmcnt(0)" ::: "memory");
        __builtin_amdgcn_sched_barrier(0);
        #pragma unroll
        for (int ks = 0; ks < 2; ks++){        // GEMM2 swapped: H^T (d rows, i=l15 cols)
            bf16x8 pf = *(const bf16x8*)&Pl[w][l15][ks*32 + quad*8];
            #pragma unroll
            for (int dt = 0; dt < 4; dt++){
                bf16x8 xt = *(const bf16x8*)&XWtL[dt*16 + l15][jt*64 + ks*32 + quad*8];
                hacc[dt] = __builtin_amdgcn_mfma_f32_16x16x32_bf16(xt, pf, hacc[dt], 0, 0, 0);
            }
        }
    }
    // ---- store: f in-lane -> float4 stores ----
    float* Hrow = H + (size_t)(b*NN + irow)*FD;
    #pragma unroll
    for (int dt = 0; dt < 4; dt++){
        float4 hv = { hacc[dt][0] + bwv[dt].x, hacc[dt][1] + bwv[dt].y,
                      hacc[dt][2] + bwv[dt].z, hacc[dt][3] + bwv[dt].w };
        *(float4*)&Hrow[dt*16 + quad*4] = hv;
    }
}

extern "C" void kernel_launch(void* const* d_in, const int* in_sizes, int n_in,
                              void* d_out, int out_size, void* d_ws, size_t ws_size,
                              hipStream_t stream){
    const float* X      = (const float*)d_in[0];
    const float* A      = (const float*)d_in[1];
    const int*   N      = (const int*)  d_in[2];
    const float* W      = (const float*)d_in[3];
    const float* a      = (const float*)d_in[4];
    const float* bias_W = (const float*)d_in[5];
    const float* bias_a = (const float*)d_in[6];
    float* H = (float*)d_out;
    (void)d_ws; (void)ws_size;                 // workspace intentionally unused

    k_fused<<<dim3(BB, 4), 512, 0, stream>>>(X, A, W, a, N, bias_a, bias_W, H);
}